// Round 8
// baseline (638.458 us; speedup 1.0000x reference)
//
#include <hip/hip_runtime.h>
#include <hip/hip_bf16.h>
#include <math.h>

// SpatialAttention B=8, C_IN=256 (d_v), C_OUT=128 (d_qk), N=4096.
// Round 15: OCCUPANCY play. flash: V moved from LDS-DMA to registers (r3's
// correctness-proven dataflow) -> LDS 76.3KB -> 26.9KB (K double 16K +
// P double 10K + Lsh), __launch_bounds__(256,4) -> 4-5 blocks/CU instead
// of 2. r3 ran this dataflow at 2 blocks/CU and lost to barrier drains;
// the freed LDS was never spent. Now every vmcnt(0) drain in one block is
// covered by 3-4 other resident blocks. K double-buffer distance-1 (r1-
// proven WAR: write issued post-barrier, last read pre-barrier), P double
// (r1-proven), V reg sets alternate even/odd tiles, reloaded after last use.
// Q-projection stays fused in the prologue (r14 win). kv_prep/cvt_w frozen.
//   cvt_w  : Wq*log2e, Wk -> fp16; bqs = bq*log2e
//   kv_prep: b -> Ktt (swizzled tiled fp16) + Vb (bf16)
//   flash  : Q-proj prologue; S mfma f16, P = 2^(S') unnormalized bf16,
//            PV mfma bf16 (V from VGPRs), divide-by-l epilogue.

#define B_   8
#define CIN  256
#define COUT 128
#define NN   4096

typedef _Float16 half8  __attribute__((ext_vector_type(8)));
typedef short    short8 __attribute__((ext_vector_type(8)));
typedef float    f32x4  __attribute__((ext_vector_type(4)));

#define LOG2E 1.44269504088896340736f

__device__ __forceinline__ unsigned short f2h(float f) {
    union { _Float16 h; unsigned short u; } v; v.h = (_Float16)f;
    return v.u;
}
// packed f32x2 -> bf16x2 in one VALU op (no builtin on gfx950; inline asm)
__device__ __forceinline__ unsigned int cvt_pk_bf16(float lo, float hi) {
    unsigned int r;
    asm("v_cvt_pk_bf16_f32 %0, %1, %2" : "=v"(r) : "v"(lo), "v"(hi));
    return r;
}
// packed f32x2 -> f16x2 (RTZ) in one VALU op; builtin returns __fp16x2
__device__ __forceinline__ unsigned int pkrtz(float lo, float hi) {
    typedef __fp16 fp16x2 __attribute__((ext_vector_type(2)));
    union { fp16x2 h; unsigned int u; } c;
    c.h = __builtin_amdgcn_cvt_pkrtz(lo, hi);
    return c.u;
}
// lane^1 exchange on the VALU pipe: DPP quad_perm [1,0,3,2] (ctrl 0xB1)
__device__ __forceinline__ float dpp_xor1(float x) {
    union { float f; int i; } u; u.f = x;
    u.i = __builtin_amdgcn_mov_dpp(u.i, 0xB1, 0xF, 0xF, true);
    return u.f;
}
// async 16B global->LDS; LDS dest = wave-uniform base + lane*16
__device__ __forceinline__ void dma16(void* lds, const void* g) {
    __builtin_amdgcn_global_load_lds(
        (const __attribute__((address_space(1))) unsigned int*)g,
        (__attribute__((address_space(3))) unsigned int*)lds,
        16, 0, 0);
}

// ---- weights: Whq = Wq*log2e (fp16), Whk = Wk (fp16); bqs = bq*log2e ----
__global__ __launch_bounds__(256) void cvt_w(const float* __restrict__ Wq,
                                             const float* __restrict__ Wk,
                                             const float* __restrict__ bq,
                                             _Float16* __restrict__ Whq,
                                             _Float16* __restrict__ Whk,
                                             float* __restrict__ bqs) {
    const int bx = blockIdx.x, t = threadIdx.x;
    const int isK = (bx >= 32);
    const float* src = isK ? Wk : Wq;
    _Float16* dst = isK ? Whk : Whq;
    const float scale = isK ? 1.0f : LOG2E;
    const int idx = (bx & 31) * 256 + t;
    float4 v = ((const float4*)src)[idx];
    unsigned long long pk = (unsigned long long)f2h(v.x * scale)
                          | ((unsigned long long)f2h(v.y * scale) << 16)
                          | ((unsigned long long)f2h(v.z * scale) << 32)
                          | ((unsigned long long)f2h(v.w * scale) << 48);
    ((unsigned long long*)dst)[idx] = pk;
    if (bx == 0 && t < COUT) bqs[t] = bq[t] * LOG2E;
}

// ---- K/V prep: b -> Ktt (swizzled tiled) + Vb (bf16). 512 blocks. ----
__global__ __launch_bounds__(256) void kv_prep(
        const float* __restrict__ Bv,    // [B][CIN][NN] fp32
        const _Float16* __restrict__ Whk,// [COUT][CIN] fp16
        const float* __restrict__ bk,    // [COUT] fp32
        _Float16* __restrict__ Ktt,      // tiled K fp16
        unsigned short* __restrict__ Vb) // [B][CIN][NN] bf16
{
    __shared__ __align__(16) unsigned short T[64 * 136];
    const int bx = blockIdx.x;
    const int b  = bx >> 6, n0 = (bx & 63) << 6;
    const int t  = threadIdx.x;

    // Vb pass: bf16 convert + store; warms L2 for the A-loads below
    {
        const int cr = t >> 2;
        const int nch = (t & 3) << 4;
#pragma unroll
        for (int it = 0; it < 4; ++it) {
            const int c = it * 64 + cr;
            const float* src = Bv + ((size_t)(b * CIN + c) * NN + n0 + nch);
            unsigned int o2[8];
#pragma unroll
            for (int k = 0; k < 4; ++k) {
                float4 f = *(const float4*)(src + k * 4);
                o2[k * 2]     = cvt_pk_bf16(f.x, f.y);
                o2[k * 2 + 1] = cvt_pk_bf16(f.z, f.w);
            }
            unsigned short* dst = Vb + (size_t)(b * CIN + c) * NN + n0 + nch;
            *(int4*)dst = *(int4*)&o2[0];
            *(int4*)(dst + 8) = *(int4*)&o2[4];
        }
    }

    const int w = t >> 6, lane = t & 63, l15 = lane & 15, quad = lane >> 4, q8 = quad * 8;

    // A fragments from global: lane holds Bv[c = s*32 + q8 + j][n0 + w*16 + l15]
    half8 a[8];
    {
        const float* Xa = Bv + ((size_t)(b * CIN + q8) * NN) + n0 + w * 16 + l15;
#pragma unroll
        for (int s = 0; s < 8; ++s) {
            const float* xs = Xa + (size_t)s * 32 * NN;
            float av[8];
#pragma unroll
            for (int j = 0; j < 8; ++j) av[j] = xs[(size_t)j * NN];
            union { half8 h; unsigned int u[4]; } af;
#pragma unroll
            for (int j = 0; j < 4; ++j) af.u[j] = pkrtz(av[2 * j], av[2 * j + 1]);
            a[s] = af.h;
        }
    }

    f32x4 D[8];
#pragma unroll
    for (int og = 0; og < 8; ++og) D[og] = (f32x4){0.f, 0.f, 0.f, 0.f};
    const _Float16* wbase = Whk + (size_t)l15 * CIN + q8;
#pragma unroll
    for (int s = 0; s < 8; ++s) {
        const _Float16* wp = wbase + s * 32;
#pragma unroll
        for (int og = 0; og < 8; ++og) {
            half8 wfv = *(const half8*)(wp + og * 16 * CIN);
            D[og] = __builtin_amdgcn_mfma_f32_16x16x32_f16(a[s], wfv, D[og], 0, 0, 0);
        }
    }

    // epilogue: tiled-swizzled K layout staging + contiguous 16KB dump
    const int nrow = w * 16 + quad * 4;
#pragma unroll
    for (int og = 0; og < 8; ++og) {
        const int o = og * 16 + l15;
        const float bo = bk[o];
        const int c = o >> 3, j = o & 7;
        const int sw = (c & 7) << 2;
#pragma unroll
        for (int r2 = 0; r2 < 4; ++r2) {
            const int n = nrow + r2;
            const int tl = n >> 5, m = n & 31;
            T[tl * 4096 + (c * 32 + ((m + sw) & 31)) * 8 + j] = f2h(D[og][r2] + bo);
        }
    }
    __syncthreads();
    _Float16* dstk = Ktt + ((size_t)(b * 128 + (n0 >> 5)) * 4096 + t * 32);
    const unsigned short* srck = T + t * 32;
#pragma unroll
    for (int k = 0; k < 4; ++k)
        ((int4*)dstk)[k] = ((const int4*)srck)[k];
}

// ---- flash attention + fused Q-projection prologue; V in registers ----
// p fp32 [b][256][4096]; Whq fp16 prescaled log2e; bqs prescaled;
// Ktt fp16 swizzled-tiled; V bf16 [b][256][4096]; out fp32 [b][256][4096]
// LDS 26.9KB: K double(8KBx2) + P double(5KBx2) + Lsh; prologue T(17.4KB)
// aliases the K region. 4+ blocks/CU at ~120 VGPR.
__global__ __launch_bounds__(256, 4) void flash_kernel(const float* __restrict__ Pin,
                                                       const _Float16* __restrict__ Whq,
                                                       const float* __restrict__ bqs,
                                                       const _Float16* __restrict__ Ktt,
                                                       const unsigned short* __restrict__ V,
                                                       float* __restrict__ out) {
    __shared__ __align__(16) char SH[27136];
    _Float16*       K0sh = (_Float16*)(SH);
    _Float16*       K1sh = (_Float16*)(SH + 8192);
    unsigned short* P0sh = (unsigned short*)(SH + 16384);
    unsigned short* P1sh = (unsigned short*)(SH + 21504);
    float*          Lsh  = (float*)(SH + 26624);
    unsigned short* T    = (unsigned short*)SH;    // prologue staging (aliased)

    const int bx   = blockIdx.x;          // 512 = B * 64 q-tiles
    const int b    = bx >> 6;
    const int q0   = (bx & 63) << 6;
    const int t    = threadIdx.x;
    const int w    = t >> 6;
    const int lane = t & 63;
    const int l15  = lane & 15;
    const int quad = lane >> 4;
    const int q8   = quad * 8;

    const _Float16* Kb = Ktt + (size_t)b * 128 * 4096;   // 128 tiles x 4096 halfs
    const unsigned short* Vg = V + (size_t)b * CIN * NN;

    // ---- fused Q-projection: Qf computed from p directly ----
    half8 Qf[4];
    {
        half8 a[8];
        const float* Xa = Pin + ((size_t)(b * CIN + q8) * NN) + q0 + w * 16 + l15;
#pragma unroll
        for (int s = 0; s < 8; ++s) {
            const float* xs = Xa + (size_t)s * 32 * NN;
            float av[8];
#pragma unroll
            for (int j = 0; j < 8; ++j) av[j] = xs[(size_t)j * NN];
            union { half8 h; unsigned int u[4]; } af;
#pragma unroll
            for (int j = 0; j < 4; ++j) af.u[j] = pkrtz(av[2 * j], av[2 * j + 1]);
            a[s] = af.h;
        }
        f32x4 D[8];
#pragma unroll
        for (int og = 0; og < 8; ++og) D[og] = (f32x4){0.f, 0.f, 0.f, 0.f};
        const _Float16* wbase = Whq + (size_t)l15 * CIN + q8;
#pragma unroll
        for (int s = 0; s < 8; ++s) {
            const _Float16* wp = wbase + s * 32;
#pragma unroll
            for (int og = 0; og < 8; ++og) {
                half8 wfv = *(const half8*)(wp + og * 16 * CIN);
                D[og] = __builtin_amdgcn_mfma_f32_16x16x32_f16(a[s], wfv, D[og], 0, 0, 0);
            }
        }
        // stage Q^T -> [n][o] (row stride 136 halfs), transpose via LDS
        const int nrow = w * 16 + quad * 4;
#pragma unroll
        for (int og = 0; og < 8; ++og) {
            const int o = og * 16 + l15;
            const float bo = bqs[o];
#pragma unroll
            for (int r2 = 0; r2 < 4; ++r2)
                T[(nrow + r2) * 136 + o] = f2h(D[og][r2] + bo);
        }
        __syncthreads();
#pragma unroll
        for (int s = 0; s < 4; ++s)
            Qf[s] = *(const half8*)&T[(w * 16 + l15) * 136 + s * 32 + q8];
        __syncthreads();   // T dead; K DMA below may overwrite the region
    }

    f32x4 O[16];   // O[ni*4+cj]: n-block ni (16 n), c = w*64 + cj*16 + l15
#pragma unroll
    for (int i = 0; i < 16; ++i) O[i] = (f32x4){0.f, 0.f, 0.f, 0.f};
    float lsum[4] = {0.f, 0.f, 0.f, 0.f};

    // V register fragments: lane reads V[c = w*64 + cj*16 + l15][kt*32 + q8..+8]
    const unsigned short* Vlane = Vg + (size_t)(w * 64 + l15) * NN + q8;
    short8 VA[4], VB[4];

    auto issueK = [&](int kt, _Float16* Kd) {
        const _Float16* gk = Kb + (size_t)kt * 4096;
        dma16(Kd + (w * 2 + 0) * 512, gk + (w * 2 + 0) * 512 + lane * 8);
        dma16(Kd + (w * 2 + 1) * 512, gk + (w * 2 + 1) * 512 + lane * 8);
    };
    auto loadV = [&](int kt, short8* Vd) {
#pragma unroll
        for (int cj = 0; cj < 4; ++cj)
            Vd[cj] = *(const short8*)(Vlane + (size_t)cj * 16 * NN + kt * 32);
    };

    // one k-tile (32 keys), single barrier:
    //   issueK(kt+1)->Kn ; S from Kc ; exp ; pack -> Pc ; BARRIER
    //   (drains K(kt+1) DMA + this wave's V reg loads) ; PV from Pc,Vregs ;
    //   loadV(kt+2) into the reg set PV just freed.
    auto halfstep = [&](int kt, const _Float16* Kc, _Float16* Kn,
                        unsigned short* Pc, short8* Vcur) {
        if (kt + 1 < 128) issueK(kt + 1, Kn);     // flies during S; drains at barrier

        // ---- S' = (Q*log2e) K^T : wave's 16 n rows x 32 m ----
        f32x4 S0 = {0.f, 0.f, 0.f, 0.f}, S1 = {0.f, 0.f, 0.f, 0.f};
        __builtin_amdgcn_s_setprio(1);
#pragma unroll
        for (int s = 0; s < 4; ++s) {
            const int kc = 4 * s + quad;          // K k-chunk (8 o's)
            const int sw = (kc & 7) << 2;
            const int x0 = (l15 + sw) & 31;
            half8 kf0 = *(const half8*)(Kc + (kc * 32 + x0) * 8);
            half8 kf1 = *(const half8*)(Kc + (kc * 32 + (x0 ^ 16)) * 8);
            S0 = __builtin_amdgcn_mfma_f32_16x16x32_f16(Qf[s], kf0, S0, 0, 0, 0);
            S1 = __builtin_amdgcn_mfma_f32_16x16x32_f16(Qf[s], kf1, S1, 0, 0, 0);
        }
        __builtin_amdgcn_s_setprio(0);

        // ---- P = 2^S' (unnormalized e^S); accumulate l ----
        f32x4 E0, E1;
#pragma unroll
        for (int r = 0; r < 4; ++r) {
            E0[r] = exp2f(S0[r]);
            E1[r] = exp2f(S1[r]);
            lsum[r] += E0[r] + E1[r];
        }
        // lane^1 exchange via DPP (VALU), pack via v_cvt_pk_bf16_f32
        {
            f32x4 P0, P1;
#pragma unroll
            for (int r = 0; r < 4; ++r) { P0[r] = dpp_xor1(E0[r]); P1[r] = dpp_xor1(E1[r]); }
            const int odd = l15 & 1;
            unsigned short* wp0 = Pc + w * 640
                                + (((quad << 2) + (odd << 1)) * 40) + (l15 & ~1);
            unsigned int pk0 = cvt_pk_bf16(odd ? P0[2] : E0[0], odd ? E0[2] : P0[0]);
            unsigned int pk1 = cvt_pk_bf16(odd ? P0[3] : E0[1], odd ? E0[3] : P0[1]);
            unsigned int pk2 = cvt_pk_bf16(odd ? P1[2] : E1[0], odd ? E1[2] : P1[0]);
            unsigned int pk3 = cvt_pk_bf16(odd ? P1[3] : E1[1], odd ? E1[3] : P1[1]);
            *(unsigned int*)&wp0[0]  = pk0;
            *(unsigned int*)&wp0[40] = pk1;
            *(unsigned int*)&wp0[16] = pk2;
            *(unsigned int*)&wp0[56] = pk3;
        }

        __syncthreads();   // P visible; K(kt+1) DMA drained

        // ---- PV: wave owns c-slice w*64..+63, all 64 n; V from registers ----
        {
            short8 pf[4];
#pragma unroll
            for (int ni = 0; ni < 4; ++ni)
                pf[ni] = *(const short8*)(Pc + (ni * 16 + l15) * 40 + q8);
            __builtin_amdgcn_s_setprio(1);
#pragma unroll
            for (int cj = 0; cj < 4; ++cj) {
                short8 vf = Vcur[cj];
#pragma unroll
                for (int ni = 0; ni < 4; ++ni)
                    O[ni * 4 + cj] = __builtin_amdgcn_mfma_f32_16x16x32_bf16(pf[ni], vf, O[ni * 4 + cj], 0, 0, 0);
            }
            __builtin_amdgcn_s_setprio(0);
        }
        // reload this reg set for tile kt+2 (registers: same-thread WAR only)
        if (kt + 2 < 128) loadV(kt + 2, Vcur);
    };

    issueK(0, K0sh);
    loadV(0, VA);
    loadV(1, VB);
    __syncthreads();   // K0 DMA + VA,VB loads drained

#pragma unroll 1
    for (int kt = 0; kt < 128; kt += 2) {
        halfstep(kt,     K0sh, K1sh, P0sh, VA);
        halfstep(kt + 1, K1sh, K0sh, P1sh, VB);
    }

    // ---- epilogue: row sums -> Lsh, divide, vectorized store ----
#pragma unroll
    for (int r = 0; r < 4; ++r) {
        float s = lsum[r];
        s += __shfl_xor(s, 1);
        s += __shfl_xor(s, 2);
        s += __shfl_xor(s, 4);
        s += __shfl_xor(s, 8);
        if (l15 == 0) Lsh[w * 16 + (quad << 2) + r] = s;
    }
    __syncthreads();
    float* ob = out + (size_t)b * CIN * NN + q0;
#pragma unroll
    for (int ni = 0; ni < 4; ++ni) {
        const f32x4 lv = *(const f32x4*)&Lsh[ni * 16 + (quad << 2)];
        f32x4 linv;
#pragma unroll
        for (int r = 0; r < 4; ++r) linv[r] = 1.0f / lv[r];
        const int nb = ni * 16 + (quad << 2);
#pragma unroll
        for (int cj = 0; cj < 4; ++cj) {
            const int c = w * 64 + cj * 16 + l15;
            f32x4 val = O[ni * 4 + cj];
#pragma unroll
            for (int r = 0; r < 4; ++r) val[r] *= linv[r];
            *(f32x4*)(ob + (size_t)c * NN + nb) = val;
        }
    }
}

extern "C" void kernel_launch(void* const* d_in, const int* in_sizes, int n_in,
                              void* d_out, int out_size, void* d_ws, size_t ws_size,
                              hipStream_t stream) {
    const float* p  = (const float*)d_in[0];
    const float* bv = (const float*)d_in[1];
    const float* Wq = (const float*)d_in[2];
    const float* bq = (const float*)d_in[3];
    const float* Wk = (const float*)d_in[4];
    const float* bk = (const float*)d_in[5];
    float* outp = (float*)d_out;

    char* ws = (char*)d_ws;
    const size_t szK = (size_t)B_ * NN * COUT * 2;   // 8.4 MB (fp16 tiled K)
    const size_t szV = (size_t)B_ * NN * CIN * 2;    // 16.8 MB (bf16)
    const size_t szW = (size_t)COUT * CIN * 2;       // 64 KB
    _Float16*       Ktt = (_Float16*)ws;
    unsigned short* Vb  = (unsigned short*)(ws + szK);
    _Float16*       Whq = (_Float16*)(ws + szK + szV);
    _Float16*       Whk = (_Float16*)(ws + szK + szV + szW);
    float*          bqs = (float*)(ws + szK + szV + 2 * szW);

    cvt_w<<<64, 256, 0, stream>>>(Wq, Wk, bq, Whq, Whk, bqs);
    kv_prep<<<512, 256, 0, stream>>>(bv, Whk, bk, Ktt, Vb);
    flash_kernel<<<512, 256, 0, stream>>>(p, Whq, bqs, Ktt, Vb, outp);
}

// Round 9
// 274.408 us; speedup vs baseline: 2.3267x; 2.3267x over previous
//
#include <hip/hip_runtime.h>
#include <hip/hip_bf16.h>
#include <math.h>

// SpatialAttention B=8, C_IN=256 (d_v), C_OUT=128 (d_qk), N=4096.
// Round 16 (= r15 with the register budget fixed): __launch_bounds__(256,3).
// r15's (256,4) set the unified VGPR+AGPR budget to 128 while the kernel
// needs ~152 (64 AGPR accumulator + ~88 VGPR) -> 580MB of scratch spill
// (WRITE_SIZE 613MB, 3x slowdown). (256,3) gives a 170-reg budget: no
// spill, 3 blocks/CU (LDS 27KB, 81KB total) vs r14's 2 -> each barrier
// vmcnt(0) drain covered by 2 other blocks' compute.
// Structure otherwise identical to r15 (passed correctness): V in registers
// (c-split per wave, loadV(kt+2) after last use), K LDS double-buffer DMA
// distance-1, P LDS double, ONE barrier per k-tile, fused Q-proj prologue.
//   cvt_w  : Wq*log2e, Wk -> fp16; bqs = bq*log2e
//   kv_prep: b -> Ktt (swizzled tiled fp16) + Vb (bf16)
//   flash  : Q-proj prologue; S mfma f16, P = 2^(S') unnormalized bf16,
//            PV mfma bf16 (V from VGPRs), divide-by-l epilogue.

#define B_   8
#define CIN  256
#define COUT 128
#define NN   4096

typedef _Float16 half8  __attribute__((ext_vector_type(8)));
typedef short    short8 __attribute__((ext_vector_type(8)));
typedef float    f32x4  __attribute__((ext_vector_type(4)));

#define LOG2E 1.44269504088896340736f

__device__ __forceinline__ unsigned short f2h(float f) {
    union { _Float16 h; unsigned short u; } v; v.h = (_Float16)f;
    return v.u;
}
// packed f32x2 -> bf16x2 in one VALU op (no builtin on gfx950; inline asm)
__device__ __forceinline__ unsigned int cvt_pk_bf16(float lo, float hi) {
    unsigned int r;
    asm("v_cvt_pk_bf16_f32 %0, %1, %2" : "=v"(r) : "v"(lo), "v"(hi));
    return r;
}
// packed f32x2 -> f16x2 (RTZ) in one VALU op; builtin returns __fp16x2
__device__ __forceinline__ unsigned int pkrtz(float lo, float hi) {
    typedef __fp16 fp16x2 __attribute__((ext_vector_type(2)));
    union { fp16x2 h; unsigned int u; } c;
    c.h = __builtin_amdgcn_cvt_pkrtz(lo, hi);
    return c.u;
}
// lane^1 exchange on the VALU pipe: DPP quad_perm [1,0,3,2] (ctrl 0xB1)
__device__ __forceinline__ float dpp_xor1(float x) {
    union { float f; int i; } u; u.f = x;
    u.i = __builtin_amdgcn_mov_dpp(u.i, 0xB1, 0xF, 0xF, true);
    return u.f;
}
// async 16B global->LDS; LDS dest = wave-uniform base + lane*16
__device__ __forceinline__ void dma16(void* lds, const void* g) {
    __builtin_amdgcn_global_load_lds(
        (const __attribute__((address_space(1))) unsigned int*)g,
        (__attribute__((address_space(3))) unsigned int*)lds,
        16, 0, 0);
}

// ---- weights: Whq = Wq*log2e (fp16), Whk = Wk (fp16); bqs = bq*log2e ----
__global__ __launch_bounds__(256) void cvt_w(const float* __restrict__ Wq,
                                             const float* __restrict__ Wk,
                                             const float* __restrict__ bq,
                                             _Float16* __restrict__ Whq,
                                             _Float16* __restrict__ Whk,
                                             float* __restrict__ bqs) {
    const int bx = blockIdx.x, t = threadIdx.x;
    const int isK = (bx >= 32);
    const float* src = isK ? Wk : Wq;
    _Float16* dst = isK ? Whk : Whq;
    const float scale = isK ? 1.0f : LOG2E;
    const int idx = (bx & 31) * 256 + t;
    float4 v = ((const float4*)src)[idx];
    unsigned long long pk = (unsigned long long)f2h(v.x * scale)
                          | ((unsigned long long)f2h(v.y * scale) << 16)
                          | ((unsigned long long)f2h(v.z * scale) << 32)
                          | ((unsigned long long)f2h(v.w * scale) << 48);
    ((unsigned long long*)dst)[idx] = pk;
    if (bx == 0 && t < COUT) bqs[t] = bq[t] * LOG2E;
}

// ---- K/V prep: b -> Ktt (swizzled tiled) + Vb (bf16). 512 blocks. ----
__global__ __launch_bounds__(256) void kv_prep(
        const float* __restrict__ Bv,    // [B][CIN][NN] fp32
        const _Float16* __restrict__ Whk,// [COUT][CIN] fp16
        const float* __restrict__ bk,    // [COUT] fp32
        _Float16* __restrict__ Ktt,      // tiled K fp16
        unsigned short* __restrict__ Vb) // [B][CIN][NN] bf16
{
    __shared__ __align__(16) unsigned short T[64 * 136];
    const int bx = blockIdx.x;
    const int b  = bx >> 6, n0 = (bx & 63) << 6;
    const int t  = threadIdx.x;

    // Vb pass: bf16 convert + store; warms L2 for the A-loads below
    {
        const int cr = t >> 2;
        const int nch = (t & 3) << 4;
#pragma unroll
        for (int it = 0; it < 4; ++it) {
            const int c = it * 64 + cr;
            const float* src = Bv + ((size_t)(b * CIN + c) * NN + n0 + nch);
            unsigned int o2[8];
#pragma unroll
            for (int k = 0; k < 4; ++k) {
                float4 f = *(const float4*)(src + k * 4);
                o2[k * 2]     = cvt_pk_bf16(f.x, f.y);
                o2[k * 2 + 1] = cvt_pk_bf16(f.z, f.w);
            }
            unsigned short* dst = Vb + (size_t)(b * CIN + c) * NN + n0 + nch;
            *(int4*)dst = *(int4*)&o2[0];
            *(int4*)(dst + 8) = *(int4*)&o2[4];
        }
    }

    const int w = t >> 6, lane = t & 63, l15 = lane & 15, quad = lane >> 4, q8 = quad * 8;

    // A fragments from global: lane holds Bv[c = s*32 + q8 + j][n0 + w*16 + l15]
    half8 a[8];
    {
        const float* Xa = Bv + ((size_t)(b * CIN + q8) * NN) + n0 + w * 16 + l15;
#pragma unroll
        for (int s = 0; s < 8; ++s) {
            const float* xs = Xa + (size_t)s * 32 * NN;
            float av[8];
#pragma unroll
            for (int j = 0; j < 8; ++j) av[j] = xs[(size_t)j * NN];
            union { half8 h; unsigned int u[4]; } af;
#pragma unroll
            for (int j = 0; j < 4; ++j) af.u[j] = pkrtz(av[2 * j], av[2 * j + 1]);
            a[s] = af.h;
        }
    }

    f32x4 D[8];
#pragma unroll
    for (int og = 0; og < 8; ++og) D[og] = (f32x4){0.f, 0.f, 0.f, 0.f};
    const _Float16* wbase = Whk + (size_t)l15 * CIN + q8;
#pragma unroll
    for (int s = 0; s < 8; ++s) {
        const _Float16* wp = wbase + s * 32;
#pragma unroll
        for (int og = 0; og < 8; ++og) {
            half8 wfv = *(const half8*)(wp + og * 16 * CIN);
            D[og] = __builtin_amdgcn_mfma_f32_16x16x32_f16(a[s], wfv, D[og], 0, 0, 0);
        }
    }

    // epilogue: tiled-swizzled K layout staging + contiguous 16KB dump
    const int nrow = w * 16 + quad * 4;
#pragma unroll
    for (int og = 0; og < 8; ++og) {
        const int o = og * 16 + l15;
        const float bo = bk[o];
        const int c = o >> 3, j = o & 7;
        const int sw = (c & 7) << 2;
#pragma unroll
        for (int r2 = 0; r2 < 4; ++r2) {
            const int n = nrow + r2;
            const int tl = n >> 5, m = n & 31;
            T[tl * 4096 + (c * 32 + ((m + sw) & 31)) * 8 + j] = f2h(D[og][r2] + bo);
        }
    }
    __syncthreads();
    _Float16* dstk = Ktt + ((size_t)(b * 128 + (n0 >> 5)) * 4096 + t * 32);
    const unsigned short* srck = T + t * 32;
#pragma unroll
    for (int k = 0; k < 4; ++k)
        ((int4*)dstk)[k] = ((const int4*)srck)[k];
}

// ---- flash attention + fused Q-projection prologue; V in registers ----
// p fp32 [b][256][4096]; Whq fp16 prescaled log2e; bqs prescaled;
// Ktt fp16 swizzled-tiled; V bf16 [b][256][4096]; out fp32 [b][256][4096]
// LDS 26.5KB: K double(8KBx2) + P double(5KBx2) + Lsh; prologue T(17.4KB)
// aliases the K region. 3 blocks/CU at <=170 unified regs (256,3).
__global__ __launch_bounds__(256, 3) void flash_kernel(const float* __restrict__ Pin,
                                                       const _Float16* __restrict__ Whq,
                                                       const float* __restrict__ bqs,
                                                       const _Float16* __restrict__ Ktt,
                                                       const unsigned short* __restrict__ V,
                                                       float* __restrict__ out) {
    __shared__ __align__(16) char SH[27136];
    _Float16*       K0sh = (_Float16*)(SH);
    _Float16*       K1sh = (_Float16*)(SH + 8192);
    unsigned short* P0sh = (unsigned short*)(SH + 16384);
    unsigned short* P1sh = (unsigned short*)(SH + 21504);
    float*          Lsh  = (float*)(SH + 26624);
    unsigned short* T    = (unsigned short*)SH;    // prologue staging (aliased)

    const int bx   = blockIdx.x;          // 512 = B * 64 q-tiles
    const int b    = bx >> 6;
    const int q0   = (bx & 63) << 6;
    const int t    = threadIdx.x;
    const int w    = t >> 6;
    const int lane = t & 63;
    const int l15  = lane & 15;
    const int quad = lane >> 4;
    const int q8   = quad * 8;

    const _Float16* Kb = Ktt + (size_t)b * 128 * 4096;   // 128 tiles x 4096 halfs
    const unsigned short* Vg = V + (size_t)b * CIN * NN;

    // ---- fused Q-projection: Qf computed from p directly ----
    half8 Qf[4];
    {
        half8 a[8];
        const float* Xa = Pin + ((size_t)(b * CIN + q8) * NN) + q0 + w * 16 + l15;
#pragma unroll
        for (int s = 0; s < 8; ++s) {
            const float* xs = Xa + (size_t)s * 32 * NN;
            float av[8];
#pragma unroll
            for (int j = 0; j < 8; ++j) av[j] = xs[(size_t)j * NN];
            union { half8 h; unsigned int u[4]; } af;
#pragma unroll
            for (int j = 0; j < 4; ++j) af.u[j] = pkrtz(av[2 * j], av[2 * j + 1]);
            a[s] = af.h;
        }
        f32x4 D[8];
#pragma unroll
        for (int og = 0; og < 8; ++og) D[og] = (f32x4){0.f, 0.f, 0.f, 0.f};
        const _Float16* wbase = Whq + (size_t)l15 * CIN + q8;
#pragma unroll
        for (int s = 0; s < 8; ++s) {
            const _Float16* wp = wbase + s * 32;
#pragma unroll
            for (int og = 0; og < 8; ++og) {
                half8 wfv = *(const half8*)(wp + og * 16 * CIN);
                D[og] = __builtin_amdgcn_mfma_f32_16x16x32_f16(a[s], wfv, D[og], 0, 0, 0);
            }
        }
        // stage Q^T -> [n][o] (row stride 136 halfs), transpose via LDS
        const int nrow = w * 16 + quad * 4;
#pragma unroll
        for (int og = 0; og < 8; ++og) {
            const int o = og * 16 + l15;
            const float bo = bqs[o];
#pragma unroll
            for (int r2 = 0; r2 < 4; ++r2)
                T[(nrow + r2) * 136 + o] = f2h(D[og][r2] + bo);
        }
        __syncthreads();
#pragma unroll
        for (int s = 0; s < 4; ++s)
            Qf[s] = *(const half8*)&T[(w * 16 + l15) * 136 + s * 32 + q8];
        __syncthreads();   // T dead; K DMA below may overwrite the region
    }

    f32x4 O[16];   // O[ni*4+cj]: n-block ni (16 n), c = w*64 + cj*16 + l15
#pragma unroll
    for (int i = 0; i < 16; ++i) O[i] = (f32x4){0.f, 0.f, 0.f, 0.f};
    float lsum[4] = {0.f, 0.f, 0.f, 0.f};

    // V register fragments: lane reads V[c = w*64 + cj*16 + l15][kt*32 + q8..+8]
    const unsigned short* Vlane = Vg + (size_t)(w * 64 + l15) * NN + q8;
    short8 VA[4], VB[4];

    auto issueK = [&](int kt, _Float16* Kd) {
        const _Float16* gk = Kb + (size_t)kt * 4096;
        dma16(Kd + (w * 2 + 0) * 512, gk + (w * 2 + 0) * 512 + lane * 8);
        dma16(Kd + (w * 2 + 1) * 512, gk + (w * 2 + 1) * 512 + lane * 8);
    };
    auto loadV = [&](int kt, short8* Vd) {
#pragma unroll
        for (int cj = 0; cj < 4; ++cj)
            Vd[cj] = *(const short8*)(Vlane + (size_t)cj * 16 * NN + kt * 32);
    };

    // one k-tile (32 keys), single barrier:
    //   issueK(kt+1)->Kn ; S from Kc ; exp ; pack -> Pc ; BARRIER
    //   (drains K(kt+1) DMA + this wave's V reg loads) ; PV from Pc,Vregs ;
    //   loadV(kt+2) into the reg set PV just freed.
    auto halfstep = [&](int kt, const _Float16* Kc, _Float16* Kn,
                        unsigned short* Pc, short8* Vcur) {
        if (kt + 1 < 128) issueK(kt + 1, Kn);     // flies during S; drains at barrier

        // ---- S' = (Q*log2e) K^T : wave's 16 n rows x 32 m ----
        f32x4 S0 = {0.f, 0.f, 0.f, 0.f}, S1 = {0.f, 0.f, 0.f, 0.f};
        __builtin_amdgcn_s_setprio(1);
#pragma unroll
        for (int s = 0; s < 4; ++s) {
            const int kc = 4 * s + quad;          // K k-chunk (8 o's)
            const int sw = (kc & 7) << 2;
            const int x0 = (l15 + sw) & 31;
            half8 kf0 = *(const half8*)(Kc + (kc * 32 + x0) * 8);
            half8 kf1 = *(const half8*)(Kc + (kc * 32 + (x0 ^ 16)) * 8);
            S0 = __builtin_amdgcn_mfma_f32_16x16x32_f16(Qf[s], kf0, S0, 0, 0, 0);
            S1 = __builtin_amdgcn_mfma_f32_16x16x32_f16(Qf[s], kf1, S1, 0, 0, 0);
        }
        __builtin_amdgcn_s_setprio(0);

        // ---- P = 2^S' (unnormalized e^S); accumulate l ----
        f32x4 E0, E1;
#pragma unroll
        for (int r = 0; r < 4; ++r) {
            E0[r] = exp2f(S0[r]);
            E1[r] = exp2f(S1[r]);
            lsum[r] += E0[r] + E1[r];
        }
        // lane^1 exchange via DPP (VALU), pack via v_cvt_pk_bf16_f32
        {
            f32x4 P0, P1;
#pragma unroll
            for (int r = 0; r < 4; ++r) { P0[r] = dpp_xor1(E0[r]); P1[r] = dpp_xor1(E1[r]); }
            const int odd = l15 & 1;
            unsigned short* wp0 = Pc + w * 640
                                + (((quad << 2) + (odd << 1)) * 40) + (l15 & ~1);
            unsigned int pk0 = cvt_pk_bf16(odd ? P0[2] : E0[0], odd ? E0[2] : P0[0]);
            unsigned int pk1 = cvt_pk_bf16(odd ? P0[3] : E0[1], odd ? E0[3] : P0[1]);
            unsigned int pk2 = cvt_pk_bf16(odd ? P1[2] : E1[0], odd ? E1[2] : P1[0]);
            unsigned int pk3 = cvt_pk_bf16(odd ? P1[3] : E1[1], odd ? E1[3] : P1[1]);
            *(unsigned int*)&wp0[0]  = pk0;
            *(unsigned int*)&wp0[40] = pk1;
            *(unsigned int*)&wp0[16] = pk2;
            *(unsigned int*)&wp0[56] = pk3;
        }

        __syncthreads();   // P visible; K(kt+1) DMA drained

        // ---- PV: wave owns c-slice w*64..+63, all 64 n; V from registers ----
        {
            short8 pf[4];
#pragma unroll
            for (int ni = 0; ni < 4; ++ni)
                pf[ni] = *(const short8*)(Pc + (ni * 16 + l15) * 40 + q8);
            __builtin_amdgcn_s_setprio(1);
#pragma unroll
            for (int cj = 0; cj < 4; ++cj) {
                short8 vf = Vcur[cj];
#pragma unroll
                for (int ni = 0; ni < 4; ++ni)
                    O[ni * 4 + cj] = __builtin_amdgcn_mfma_f32_16x16x32_bf16(pf[ni], vf, O[ni * 4 + cj], 0, 0, 0);
            }
            __builtin_amdgcn_s_setprio(0);
        }
        // reload this reg set for tile kt+2 (registers: same-thread WAR only)
        if (kt + 2 < 128) loadV(kt + 2, Vcur);
    };

    issueK(0, K0sh);
    loadV(0, VA);
    loadV(1, VB);
    __syncthreads();   // K0 DMA + VA,VB loads drained

#pragma unroll 1
    for (int kt = 0; kt < 128; kt += 2) {
        halfstep(kt,     K0sh, K1sh, P0sh, VA);
        halfstep(kt + 1, K1sh, K0sh, P1sh, VB);
    }

    // ---- epilogue: row sums -> Lsh, divide, vectorized store ----
#pragma unroll
    for (int r = 0; r < 4; ++r) {
        float s = lsum[r];
        s += __shfl_xor(s, 1);
        s += __shfl_xor(s, 2);
        s += __shfl_xor(s, 4);
        s += __shfl_xor(s, 8);
        if (l15 == 0) Lsh[w * 16 + (quad << 2) + r] = s;
    }
    __syncthreads();
    float* ob = out + (size_t)b * CIN * NN + q0;
#pragma unroll
    for (int ni = 0; ni < 4; ++ni) {
        const f32x4 lv = *(const f32x4*)&Lsh[ni * 16 + (quad << 2)];
        f32x4 linv;
#pragma unroll
        for (int r = 0; r < 4; ++r) linv[r] = 1.0f / lv[r];
        const int nb = ni * 16 + (quad << 2);
#pragma unroll
        for (int cj = 0; cj < 4; ++cj) {
            const int c = w * 64 + cj * 16 + l15;
            f32x4 val = O[ni * 4 + cj];
#pragma unroll
            for (int r = 0; r < 4; ++r) val[r] *= linv[r];
            *(f32x4*)(ob + (size_t)c * NN + nb) = val;
        }
    }
}

extern "C" void kernel_launch(void* const* d_in, const int* in_sizes, int n_in,
                              void* d_out, int out_size, void* d_ws, size_t ws_size,
                              hipStream_t stream) {
    const float* p  = (const float*)d_in[0];
    const float* bv = (const float*)d_in[1];
    const float* Wq = (const float*)d_in[2];
    const float* bq = (const float*)d_in[3];
    const float* Wk = (const float*)d_in[4];
    const float* bk = (const float*)d_in[5];
    float* outp = (float*)d_out;

    char* ws = (char*)d_ws;
    const size_t szK = (size_t)B_ * NN * COUT * 2;   // 8.4 MB (fp16 tiled K)
    const size_t szV = (size_t)B_ * NN * CIN * 2;    // 16.8 MB (bf16)
    const size_t szW = (size_t)COUT * CIN * 2;       // 64 KB
    _Float16*       Ktt = (_Float16*)ws;
    unsigned short* Vb  = (unsigned short*)(ws + szK);
    _Float16*       Whq = (_Float16*)(ws + szK + szV);
    _Float16*       Whk = (_Float16*)(ws + szK + szV + szW);
    float*          bqs = (float*)(ws + szK + szV + 2 * szW);

    cvt_w<<<64, 256, 0, stream>>>(Wq, Wk, bq, Whq, Whk, bqs);
    kv_prep<<<512, 256, 0, stream>>>(bv, Whk, bk, Ktt, Vb);
    flash_kernel<<<512, 256, 0, stream>>>(p, Whq, bqs, Ktt, Vb, outp);
}